// Round 3
// baseline (909.808 us; speedup 1.0000x reference)
//
#include <hip/hip_runtime.h>
#include <math.h>

#define Bn 16
#define Ln 2500
#define En 100
#define FM 50
#define Yn 8921
#define KS 10
#define LP 2501
#define NT 40              // 40 tiles of 64 l (2560 >= 2501)
#define TILE_BYTES 19456   // hA 10240 + hT 9216
#define TILE_SHORTS 9728
#define HT_OFF 5120        // shorts
#define CH_FULL 19         // 1KB chunks per full tile
#define CH_A 10            // chunks covering hA only
#define NW 8               // waves per K2 block
#define YB 128             // y per K2 block
#define NYB 70             // ceil(8921/128)

typedef __attribute__((ext_vector_type(8))) short short8;
typedef __attribute__((ext_vector_type(4))) float f32x4;

union S8 { short8 v; long l2[2]; short s[8]; };

__device__ __forceinline__ short f2bf(float f){
  unsigned u = __float_as_uint(f);
  unsigned r = (u + 0x7fffu + ((u >> 16) & 1u)) >> 16;
  return (short)r;
}

// async 16B/lane global->LDS
__device__ __forceinline__ void g2l16(const void* g, void* l){
  __builtin_amdgcn_global_load_lds(
      (const __attribute__((address_space(1))) unsigned int*)g,
      (__attribute__((address_space(3))) unsigned int*)l, 16, 0, 0);
}

__device__ __forceinline__ void stage_chunks(const char* __restrict__ gbase,
                                             char* lbase, int wave, int lane, int nch){
  for (int chunk = wave; chunk < nch; chunk += NW)
    g2l16(gbase + chunk * 1024 + lane * 16, lbase + chunk * 1024 + lane * 16);
}

// ---------------- K0: transpose conv_w (Fm,E,K) -> WT[e*10+k][f(64 pad0)] --------------
__global__ void k0_wt(const float* __restrict__ cw, float* __restrict__ WT){
  int i = blockIdx.x * 256 + threadIdx.x;
  if (i < 64000){
    int f = i & 63, ek = i >> 6;
    WT[i] = (f < FM) ? cw[f * 1000 + ek] : 0.f;
  }
}

// ---------------- K1: conv+bias+tanh -> per-tile blob [hA pad | hT pad] bf16 -----------
__global__ __launch_bounds__(256) void k1_conv(
    const float* __restrict__ x, const float* __restrict__ WT,
    const float* __restrict__ conv_b, short* __restrict__ Hp)
{
  int t = blockIdx.x, b = blockIdx.y, tid = threadIdx.x;
  __shared__ float x_s[100 * 76];       // [e][row(73) pad 76]
  __shared__ short h_t[64 * 69];        // [l][f pad 69]

  int r0 = 64 * t - 5;
  for (int d = tid; d < 7300; d += 256){
    int row = d / 100, e = d - row * 100;
    int gr = r0 + row;
    float v = (gr >= 0 && gr < Ln) ? x[((size_t)b * Ln + gr) * 100 + e] : 0.f;
    x_s[e * 76 + row] = v;
  }
  __syncthreads();

  int f = tid & 63, lsub = tid >> 6;
  float acc[16];
#pragma unroll
  for (int j = 0; j < 16; j++) acc[j] = 0.f;

  for (int e = 0; e < 100; e++){
    float xv[25];
    const float* xr = x_s + e * 76 + lsub * 16;
#pragma unroll
    for (int i = 0; i < 6; i++){
      f32x4 q = *(const f32x4*)(xr + 4 * i);
      xv[4*i+0] = q[0]; xv[4*i+1] = q[1]; xv[4*i+2] = q[2]; xv[4*i+3] = q[3];
    }
    xv[24] = xr[24];
#pragma unroll
    for (int k = 0; k < KS; k++){
      float wv = WT[(e * 10 + k) * 64 + f];
#pragma unroll
      for (int j = 0; j < 16; j++) acc[j] += wv * xv[j + k];
    }
  }

  float bias = (f < FM) ? conv_b[f] : 0.f;
  size_t tbS = (size_t)(b * NT + t) * TILE_SHORTS;
#pragma unroll
  for (int j = 0; j < 16; j++){
    int l = lsub * 16 + j;
    int lgl = 64 * t + l;
    float hv = (lgl < LP && f < FM) ? tanhf(acc[j] + bias) : 0.f;
    short hb = f2bf(hv);
    // hA image: [fgrp(4)][l(64)][20]  (cols 16..19 are unread holes)
    Hp[tbS + (size_t)(f >> 4) * 1280 + (size_t)l * 20 + (f & 15)] = hb;
    h_t[l * 69 + f] = hb;
  }
  __syncthreads();
  int lane = tid & 63, wave = tid >> 6;
#pragma unroll
  for (int i = 0; i < 16; i++){
    int fo = wave + 4 * i;
    // hT image: [f(64)][72]  (cols 64..71 unread holes)
    Hp[tbS + HT_OFF + (size_t)fo * 72 + lane] = h_t[lane * 69 + fo];
  }
}

// ---------------- K2 fragment compute ----------------
__device__ __forceinline__ void scores_tile(const short* __restrict__ h_s,
                                            const S8 bu[2], int c, int g, f32x4 d[4])
{
#pragma unroll
  for (int ms = 0; ms < 4; ms++){
    f32x4 acc = {0.f, 0.f, 0.f, 0.f};
#pragma unroll
    for (int kf = 0; kf < 2; kf++){
      const short* pa = h_s + (2 * kf) * 1280 + (c + 16 * ms) * 20 + 4 * g;
      S8 a;
      a.l2[0] = *(const long*)pa;
      a.l2[1] = *(const long*)(pa + 1280);
      acc = __builtin_amdgcn_mfma_f32_16x16x32_bf16(a.v, bu[kf].v, acc, 0, 0, 0);
    }
    d[ms] = acc;
  }
}

// ---------------- K2: fused scores -> softmax -> alpha write -> m -> logits ------------
// 1D grid of 1120 blocks; XCD-affinity: id&7 = dispatch XCD; XCD x serves b in {x, x+8}
__global__ __launch_bounds__(512, 4) void k2_attn(
    const short* __restrict__ Hp,
    const float* __restrict__ U_w, const float* __restrict__ final_w,
    const float* __restrict__ final_b,
    float* __restrict__ logits, float* __restrict__ alpha_out)
{
  int id = blockIdx.x;
  int xcd = id & 7, r = id >> 3;            // r in [0,140)
  int b   = xcd + ((r >= NYB) ? 8 : 0);
  int y0  = ((r >= NYB) ? r - NYB : r) * YB;

  int tid = threadIdx.x;
  int lane = tid & 63, wave = tid >> 6;
  int c = lane & 15, g = lane >> 4;
  int ywave = y0 + wave * 16;

  __shared__ __align__(16) short buf[2][TILE_SHORTS];
  __shared__ float aw_s[NW][16 * 37];

  // B1 fragments from U_w (k-slot convention matches A fragments)
  S8 bu[2];
  {
    int yv = ywave + c;
#pragma unroll
    for (int kf = 0; kf < 2; kf++)
#pragma unroll
      for (int i = 0; i < 8; i++){
        int fidx = 4 * g + (i & 3) + 16 * (i >> 2) + 32 * kf;
        float v = (yv < Yn && fidx < FM) ? U_w[yv * FM + fidx] : 0.f;
        bu[kf].s[i] = f2bf(v);
      }
  }

  const char* blob = (const char*)Hp + (size_t)b * NT * TILE_BYTES;

  // ---- pass 1: S = sum_l exp(score)  (no max subtraction: |score| < ~5) ----
  float S = 0.f;
  int cur = 0;
  stage_chunks(blob, (char*)buf[0], wave, lane, CH_A);
  for (int t = 0; t < NT; t++){
    __syncthreads();                       // drains vmcnt -> buf[cur] ready
    if (t + 1 < NT)
      stage_chunks(blob + (size_t)(t + 1) * TILE_BYTES, (char*)buf[cur ^ 1], wave, lane, CH_A);
    f32x4 d[4];
    scores_tile(buf[cur], bu, c, g, d);
    if (t < NT - 1){
#pragma unroll
      for (int ms = 0; ms < 4; ms++)
#pragma unroll
        for (int r2 = 0; r2 < 4; r2++) S += __expf(d[ms][r2]);
    } else {
#pragma unroll
      for (int ms = 0; ms < 4; ms++)
#pragma unroll
        for (int r2 = 0; r2 < 4; r2++){
          int l = 64 * t + 16 * ms + 4 * g + r2;
          if (l < LP) S += __expf(d[ms][r2]);
        }
    }
    cur ^= 1;
  }
  S += __shfl_xor(S, 16);
  S += __shfl_xor(S, 32);
  float invS = 1.f / S;

  // ---- pass 2: alpha (write) + m accumulate ----
  f32x4 m2[4];
#pragma unroll
  for (int fs = 0; fs < 4; fs++) m2[fs] = (f32x4){0.f, 0.f, 0.f, 0.f};

  __syncthreads();                          // pass1 compute fully done before restage
  stage_chunks(blob, (char*)buf[cur], wave, lane, CH_FULL);
  for (int t = 0; t < NT; t++){
    __syncthreads();
    if (t + 1 < NT)
      stage_chunks(blob + (size_t)(t + 1) * TILE_BYTES, (char*)buf[cur ^ 1], wave, lane, CH_FULL);
    const short* h_s  = buf[cur];
    const short* ht_s = buf[cur] + HT_OFF;
    f32x4 d[4];
    scores_tile(h_s, bu, c, g, d);
    float a[16];
    if (t < NT - 1){
#pragma unroll
      for (int ms = 0; ms < 4; ms++)
#pragma unroll
        for (int r2 = 0; r2 < 4; r2++) a[ms * 4 + r2] = __expf(d[ms][r2]) * invS;
    } else {
#pragma unroll
      for (int ms = 0; ms < 4; ms++)
#pragma unroll
        for (int r2 = 0; r2 < 4; r2++){
          int l = 64 * t + 16 * ms + 4 * g + r2;
          a[ms * 4 + r2] = (l < LP) ? __expf(d[ms][r2]) * invS : 0.f;
        }
    }

    // GEMM2: m += alpha * h   (A2 repacked in-lane from scores^T fragments)
#pragma unroll
    for (int kl = 0; kl < 2; kl++){
      S8 a2;
#pragma unroll
      for (int i = 0; i < 8; i++)
        a2.s[i] = f2bf(a[(2 * kl + (i >> 2)) * 4 + (i & 3)]);
#pragma unroll
      for (int fs = 0; fs < 4; fs++){
        const short* pb = ht_s + (16 * fs + c) * 72 + 4 * g + 32 * kl;
        S8 b2;
        b2.l2[0] = *(const long*)pb;
        b2.l2[1] = *(const long*)(pb + 16);
        m2[fs] = __builtin_amdgcn_mfma_f32_16x16x32_bf16(a2.v, b2.v, m2[fs], 0, 0, 0);
      }
    }

    // alpha -> per-wave LDS transpose (2 rounds of 32 l), coalesced 128B-row stores
    float* aw = aw_s[wave];
#pragma unroll
    for (int ms2 = 0; ms2 < 2; ms2++){
#pragma unroll
      for (int mh = 0; mh < 2; mh++)
#pragma unroll
        for (int r2 = 0; r2 < 4; r2++)
          aw[c * 37 + 16 * mh + 4 * g + r2] = a[(2 * ms2 + mh) * 4 + r2];
      // wave-internal: compiler inserts lgkmcnt waits, no barrier needed
      int col = lane & 31;
      int jhi = lane >> 5;
#pragma unroll
      for (int j0 = 0; j0 < 16; j0 += 2){
        int j = j0 + jhi;
        int yj = ywave + j;
        int lg = 64 * t + 32 * ms2 + col;
        if (yj < Yn && lg < LP)
          alpha_out[((size_t)b * Yn + yj) * LP + lg] = aw[j * 37 + col];
      }
    }
    cur ^= 1;
  }

  // ---- epilogue: logits ----
  float part[4];
#pragma unroll
  for (int r2 = 0; r2 < 4; r2++){
    int yy = ywave + 4 * g + r2;
    float p = 0.f;
    if (yy < Yn){
#pragma unroll
      for (int fs = 0; fs < 4; fs++){
        int fcol = fs * 16 + c;
        if (fcol < FM) p += m2[fs][r2] * final_w[yy * FM + fcol];
      }
    }
#pragma unroll
    for (int off = 1; off <= 8; off <<= 1) p += __shfl_xor(p, off);
    part[r2] = p;
  }
  if (c == 0){
#pragma unroll
    for (int r2 = 0; r2 < 4; r2++){
      int yy = ywave + 4 * g + r2;
      if (yy < Yn) logits[(size_t)b * Yn + yy] = part[r2] + final_b[yy];
    }
  }
}

// ---------------- K3: log_softmax over Y + BCE loss partials ----------------
__global__ __launch_bounds__(256) void k3_lsm(
    const float* __restrict__ logits, const float* __restrict__ target,
    float* __restrict__ proba, float* __restrict__ lossp)
{
  int b = blockIdx.x, tid = threadIdx.x;
  int lane = tid & 63, wave = tid >> 6;
  __shared__ float red[4];
  const float* lg = logits + (size_t)b * Yn;
  const float* tg = target + (size_t)b * Yn;

  float m = -INFINITY;
  for (int y = tid; y < Yn; y += 256) m = fmaxf(m, lg[y]);
#pragma unroll
  for (int off = 1; off <= 32; off <<= 1) m = fmaxf(m, __shfl_xor(m, off));
  if (lane == 0) red[wave] = m;
  __syncthreads();
  m = fmaxf(fmaxf(red[0], red[1]), fmaxf(red[2], red[3]));
  __syncthreads();

  float s = 0.f;
  for (int y = tid; y < Yn; y += 256) s += __expf(lg[y] - m);
#pragma unroll
  for (int off = 1; off <= 32; off <<= 1) s += __shfl_xor(s, off);
  if (lane == 0) red[wave] = s;
  __syncthreads();
  s = red[0] + red[1] + red[2] + red[3];
  __syncthreads();
  float lse = m + logf(s);

  float ls = 0.f;
  for (int y = tid; y < Yn; y += 256){
    float xx = lg[y];
    proba[(size_t)b * Yn + y] = xx - lse;
    ls += fmaxf(xx, 0.f) - xx * tg[y] + log1pf(__expf(-fabsf(xx)));
  }
#pragma unroll
  for (int off = 1; off <= 32; off <<= 1) ls += __shfl_xor(ls, off);
  if (lane == 0) red[wave] = ls;
  __syncthreads();
  if (tid == 0) lossp[b] = red[0] + red[1] + red[2] + red[3];
}

__global__ void k4_loss(const float* __restrict__ lossp, float* __restrict__ out){
  if (threadIdx.x == 0){
    float s = 0.f;
    for (int i = 0; i < Bn; i++) s += lossp[i];
    out[142736] = s / 142736.f;
  }
}

// ---------------- launch ----------------
extern "C" void kernel_launch(void* const* d_in, const int* in_sizes, int n_in,
                              void* d_out, int out_size, void* d_ws, size_t ws_size,
                              hipStream_t stream)
{
  const float* x       = (const float*)d_in[0];
  const float* target  = (const float*)d_in[1];
  const float* conv_w  = (const float*)d_in[2];
  const float* conv_b  = (const float*)d_in[3];
  const float* U_w     = (const float*)d_in[4];
  const float* final_w = (const float*)d_in[5];
  const float* final_b = (const float*)d_in[6];
  float* out = (float*)d_out;

  char* ws = (char*)d_ws;
  short* Hp     = (short*)(ws);                 // 16*40*19456 = 12,451,840 B
  float* WT     = (float*)(ws + 12451840);      //   256,000 B
  float* logits = (float*)(ws + 12707840);      //   570,944 B
  float* lossp  = (float*)(ws + 13278784);      //        64 B

  float* proba     = out;              // B*Y
  float* alpha_out = out + 142737;     // after proba + loss

  k0_wt<<<dim3(250), dim3(256), 0, stream>>>(conv_w, WT);
  k1_conv<<<dim3(NT, Bn), dim3(256), 0, stream>>>(x, WT, conv_b, Hp);
  k2_attn<<<dim3(8 * 2 * NYB), dim3(512), 0, stream>>>(Hp, U_w, final_w, final_b,
                                                       logits, alpha_out);
  k3_lsm<<<dim3(Bn), dim3(256), 0, stream>>>(logits, target, proba, lossp);
  k4_loss<<<dim3(1), dim3(64), 0, stream>>>(lossp, out);
}

// Round 4
// 765.198 us; speedup vs baseline: 1.1890x; 1.1890x over previous
//
#include <hip/hip_runtime.h>
#include <math.h>

#define Bn 16
#define Ln 2500
#define En 100
#define FM 50
#define Yn 8921
#define KS 10
#define LP 2501
#define NT 40              // 40 tiles of 64 l (2560 >= 2501)
#define TILE_BYTES 19456   // hA 10240 + hT 9216
#define TILE_SHORTS 9728
#define HT_OFF 5120        // shorts
#define CH_FULL 19         // 1KB chunks per full tile
#define CH_A 10            // chunks covering hA only
#define NW 8               // waves per K2a block
#define YB 128             // y per K2a block
#define NYB 70             // ceil(8921/128)
#define NW2 4              // waves per K2b block
#define YB2 64             // y per K2b block
#define NYB2 140           // ceil(8921/64)

typedef __attribute__((ext_vector_type(8))) short short8;
typedef __attribute__((ext_vector_type(4))) float f32x4;

union S8 { short8 v; long l2[2]; short s[8]; };

__device__ __forceinline__ short f2bf(float f){
  unsigned u = __float_as_uint(f);
  unsigned r = (u + 0x7fffu + ((u >> 16) & 1u)) >> 16;
  return (short)r;
}

// async 16B/lane global->LDS
__device__ __forceinline__ void g2l16(const void* g, void* l){
  __builtin_amdgcn_global_load_lds(
      (const __attribute__((address_space(1))) unsigned int*)g,
      (__attribute__((address_space(3))) unsigned int*)l, 16, 0, 0);
}

__device__ __forceinline__ void stage_chunks(const char* __restrict__ gbase,
                                             char* lbase, int wave, int lane,
                                             int nch, int nw){
  for (int chunk = wave; chunk < nch; chunk += nw)
    g2l16(gbase + chunk * 1024 + lane * 16, lbase + chunk * 1024 + lane * 16);
}

// ---------------- K0: transpose conv_w (Fm,E,K) -> WT[e*10+k][f(64 pad0)] --------------
__global__ void k0_wt(const float* __restrict__ cw, float* __restrict__ WT){
  int i = blockIdx.x * 256 + threadIdx.x;
  if (i < 64000){
    int f = i & 63, ek = i >> 6;
    WT[i] = (f < FM) ? cw[f * 1000 + ek] : 0.f;
  }
}

// ---------------- K1: conv+bias+tanh -> per-tile blob [hA pad | hT pad] bf16 -----------
__global__ __launch_bounds__(256) void k1_conv(
    const float* __restrict__ x, const float* __restrict__ WT,
    const float* __restrict__ conv_b, short* __restrict__ Hp)
{
  int t = blockIdx.x, b = blockIdx.y, tid = threadIdx.x;
  __shared__ float x_s[100 * 76];       // [e][row(73) pad 76]
  __shared__ short h_t[64 * 69];        // [l][f pad 69]

  int r0 = 64 * t - 5;
  for (int d = tid; d < 7300; d += 256){
    int row = d / 100, e = d - row * 100;
    int gr = r0 + row;
    float v = (gr >= 0 && gr < Ln) ? x[((size_t)b * Ln + gr) * 100 + e] : 0.f;
    x_s[e * 76 + row] = v;
  }
  __syncthreads();

  int f = tid & 63, lsub = tid >> 6;
  float acc[16];
#pragma unroll
  for (int j = 0; j < 16; j++) acc[j] = 0.f;

  for (int e = 0; e < 100; e++){
    float xv[25];
    const float* xr = x_s + e * 76 + lsub * 16;
#pragma unroll
    for (int i = 0; i < 6; i++){
      f32x4 q = *(const f32x4*)(xr + 4 * i);
      xv[4*i+0] = q[0]; xv[4*i+1] = q[1]; xv[4*i+2] = q[2]; xv[4*i+3] = q[3];
    }
    xv[24] = xr[24];
#pragma unroll
    for (int k = 0; k < KS; k++){
      float wv = WT[(e * 10 + k) * 64 + f];
#pragma unroll
      for (int j = 0; j < 16; j++) acc[j] += wv * xv[j + k];
    }
  }

  float bias = (f < FM) ? conv_b[f] : 0.f;
  size_t tbS = (size_t)(b * NT + t) * TILE_SHORTS;
#pragma unroll
  for (int j = 0; j < 16; j++){
    int l = lsub * 16 + j;
    int lgl = 64 * t + l;
    float hv = (lgl < LP && f < FM) ? tanhf(acc[j] + bias) : 0.f;
    short hb = f2bf(hv);
    // hA image: [fgrp(4)][l(64)][20]  (cols 16..19 are unread holes)
    Hp[tbS + (size_t)(f >> 4) * 1280 + (size_t)l * 20 + (f & 15)] = hb;
    h_t[l * 69 + f] = hb;
  }
  __syncthreads();
  int lane = tid & 63, wave = tid >> 6;
#pragma unroll
  for (int i = 0; i < 16; i++){
    int fo = wave + 4 * i;
    // hT image: [f(64)][72]  (cols 64..71 unread holes)
    Hp[tbS + HT_OFF + (size_t)fo * 72 + lane] = h_t[lane * 69 + fo];
  }
}

// ---------------- shared fragment helpers ----------------
__device__ __forceinline__ void scores_tile(const short* __restrict__ h_s,
                                            const S8 bu[2], int c, int g, f32x4 d[4])
{
#pragma unroll
  for (int ms = 0; ms < 4; ms++){
    f32x4 acc = {0.f, 0.f, 0.f, 0.f};
#pragma unroll
    for (int kf = 0; kf < 2; kf++){
      const short* pa = h_s + (2 * kf) * 1280 + (c + 16 * ms) * 20 + 4 * g;
      S8 a;
      a.l2[0] = *(const long*)pa;
      a.l2[1] = *(const long*)(pa + 1280);
      acc = __builtin_amdgcn_mfma_f32_16x16x32_bf16(a.v, bu[kf].v, acc, 0, 0, 0);
    }
    d[ms] = acc;
  }
}

__device__ __forceinline__ void load_bu(const float* __restrict__ U_w,
                                        int ywave, int c, int g, S8 bu[2]){
  int yv = ywave + c;
#pragma unroll
  for (int kf = 0; kf < 2; kf++)
#pragma unroll
    for (int i = 0; i < 8; i++){
      int fidx = 4 * g + (i & 3) + 16 * (i >> 2) + 32 * kf;
      float v = (yv < Yn && fidx < FM) ? U_w[yv * FM + fidx] : 0.f;
      bu[kf].s[i] = f2bf(v);
    }
}

// ---------------- K2a: S = sum_l exp(score) -> invS ----------------
__global__ __launch_bounds__(512, 4) void k2a_sum(
    const short* __restrict__ Hp, const float* __restrict__ U_w,
    float* __restrict__ invS_out)
{
  int id = blockIdx.x;
  int xcd = id & 7, rr = id >> 3;           // rr in [0,140)
  int b   = xcd + ((rr >= NYB) ? 8 : 0);
  int y0  = ((rr >= NYB) ? rr - NYB : rr) * YB;

  int tid = threadIdx.x;
  int lane = tid & 63, wave = tid >> 6;
  int c = lane & 15, g = lane >> 4;
  int ywave = y0 + wave * 16;

  __shared__ __align__(16) short buf[2][5120];   // hA only

  S8 bu[2];
  load_bu(U_w, ywave, c, g, bu);

  const char* blob = (const char*)Hp + (size_t)b * NT * TILE_BYTES;

  float S = 0.f;
  int cur = 0;
  stage_chunks(blob, (char*)buf[0], wave, lane, CH_A, NW);
  for (int t = 0; t < NT; t++){
    __syncthreads();
    if (t + 1 < NT)
      stage_chunks(blob + (size_t)(t + 1) * TILE_BYTES, (char*)buf[cur ^ 1], wave, lane, CH_A, NW);
    f32x4 d[4];
    scores_tile(buf[cur], bu, c, g, d);
    if (t < NT - 1){
#pragma unroll
      for (int ms = 0; ms < 4; ms++)
#pragma unroll
        for (int q = 0; q < 4; q++) S += __expf(d[ms][q]);
    } else {
#pragma unroll
      for (int ms = 0; ms < 4; ms++)
#pragma unroll
        for (int q = 0; q < 4; q++){
          int l = 64 * t + 16 * ms + 4 * g + q;
          if (l < LP) S += __expf(d[ms][q]);
        }
    }
    cur ^= 1;
  }
  S += __shfl_xor(S, 16);
  S += __shfl_xor(S, 32);
  if (lane < 16){
    int yv = ywave + lane;
    if (yv < Yn) invS_out[b * Yn + yv] = 1.f / S;
  }
}

// ---------------- K2b: alpha (aligned full-line writes) + m + logits ----------------
__global__ __launch_bounds__(256, 2) void k2b_alpha(
    const short* __restrict__ Hp,
    const float* __restrict__ U_w, const float* __restrict__ final_w,
    const float* __restrict__ final_b, const float* __restrict__ invS_arr,
    float* __restrict__ logits, float* __restrict__ alpha_out)
{
  int id = blockIdx.x;
  int xcd = id & 7, rr = id >> 3;           // rr in [0,280)
  int b   = xcd + ((rr >= NYB2) ? 8 : 0);
  int y0  = ((rr >= NYB2) ? rr - NYB2 : rr) * YB2;

  int tid = threadIdx.x;
  int lane = tid & 63, wave = tid >> 6;     // wave 0..3
  int c = lane & 15, g = lane >> 4;
  int ywave = y0 + wave * 16;

  __shared__ __align__(16) short buf[2][TILE_SHORTS];
  __shared__ float awf[NW2 * 16 * 96];      // per-wave [16 rows][96]: carry<=31 + 64 new

  S8 bu[2];
  load_bu(U_w, ywave, c, g, bu);

  float invS = 0.f;
  { int yv = ywave + c; if (yv < Yn) invS = invS_arr[b * Yn + yv]; }

  // alpha row phase: global float index of (y,0) is 142737 + (b*8921+y)*2501
  // mod 32: (17 + 29*b + 5*y) & 31  -> constant carry length per row
  int Kf = (17 + 29 * b + 5 * ywave) & 31;
  int fc = (Kf + 5 * c) & 31;

  f32x4 m2[4];
#pragma unroll
  for (int fs = 0; fs < 4; fs++) m2[fs] = (f32x4){0.f, 0.f, 0.f, 0.f};

  const char* blob = (const char*)Hp + (size_t)b * NT * TILE_BYTES;
  float* aw = awf + wave * (16 * 96);

  int cur = 0;
  stage_chunks(blob, (char*)buf[0], wave, lane, CH_FULL, NW2);
  for (int t = 0; t < NT; t++){
    __syncthreads();
    if (t + 1 < NT)
      stage_chunks(blob + (size_t)(t + 1) * TILE_BYTES, (char*)buf[cur ^ 1], wave, lane, CH_FULL, NW2);
    const short* h_s  = buf[cur];
    const short* ht_s = buf[cur] + HT_OFF;
    f32x4 d[4];
    scores_tile(h_s, bu, c, g, d);
    float a[16];
    if (t < NT - 1){
#pragma unroll
      for (int ms = 0; ms < 4; ms++)
#pragma unroll
        for (int q = 0; q < 4; q++) a[ms * 4 + q] = __expf(d[ms][q]) * invS;
    } else {
#pragma unroll
      for (int ms = 0; ms < 4; ms++)
#pragma unroll
        for (int q = 0; q < 4; q++){
          int l = 64 * t + 16 * ms + 4 * g + q;
          a[ms * 4 + q] = (l < LP) ? __expf(d[ms][q]) * invS : 0.f;
        }
    }

    // GEMM2: m += alpha * h   (A2 repacked in-lane from scores^T fragments)
#pragma unroll
    for (int kl = 0; kl < 2; kl++){
      S8 a2;
#pragma unroll
      for (int i = 0; i < 8; i++)
        a2.s[i] = f2bf(a[(2 * kl + (i >> 2)) * 4 + (i & 3)]);
#pragma unroll
      for (int fs = 0; fs < 4; fs++){
        const short* pb = ht_s + (16 * fs + c) * 72 + 4 * g + 32 * kl;
        S8 b2;
        b2.l2[0] = *(const long*)pb;
        b2.l2[1] = *(const long*)(pb + 16);
        m2[fs] = __builtin_amdgcn_mfma_f32_16x16x32_bf16(a2.v, b2.v, m2[fs], 0, 0, 0);
      }
    }

    // scatter new alphas at row phase fc (positions [fc, fc+64))
#pragma unroll
    for (int ms = 0; ms < 4; ms++)
#pragma unroll
      for (int q = 0; q < 4; q++)
        aw[c * 96 + fc + 16 * ms + 4 * g + q] = a[ms * 4 + q];

    // store 64 floats per row = two full aligned 128B lines (no RFO), nontemporal
#pragma unroll
    for (int jj = 0; jj < 16; jj++){
      int fj = (Kf + 5 * jj) & 31;
      int col = 64 * t - fj + lane;
      float v = aw[jj * 96 + lane];
      int yj = ywave + jj;
      if (col >= 0 && col < LP && yj < Yn)
        __builtin_nontemporal_store(v, alpha_out + ((size_t)(b * Yn + yj)) * LP + col);
    }
    // shift carry [64, 64+fj) -> [0, fj)
#pragma unroll
    for (int jj = 0; jj < 16; jj++){
      int fj = (Kf + 5 * jj) & 31;
      if (lane < fj) aw[jj * 96 + lane] = aw[jj * 96 + 64 + lane];
    }
    cur ^= 1;
  }
  // main loop covers cols [0, 2560-fj) superset of [0,2501) since fj<=31 -> no flush

  // ---- epilogue: logits ----
  float part[4];
#pragma unroll
  for (int q = 0; q < 4; q++){
    int yy = ywave + 4 * g + q;
    float p = 0.f;
    if (yy < Yn){
#pragma unroll
      for (int fs = 0; fs < 4; fs++){
        int fcol = fs * 16 + c;
        if (fcol < FM) p += m2[fs][q] * final_w[yy * FM + fcol];
      }
    }
#pragma unroll
    for (int off = 1; off <= 8; off <<= 1) p += __shfl_xor(p, off);
    part[q] = p;
  }
  if (c == 0){
#pragma unroll
    for (int q = 0; q < 4; q++){
      int yy = ywave + 4 * g + q;
      if (yy < Yn) logits[(size_t)b * Yn + yy] = part[q] + final_b[yy];
    }
  }
}

// ---------------- K3: log_softmax over Y + BCE loss partials ----------------
__global__ __launch_bounds__(256) void k3_lsm(
    const float* __restrict__ logits, const float* __restrict__ target,
    float* __restrict__ proba, float* __restrict__ lossp)
{
  int b = blockIdx.x, tid = threadIdx.x;
  int lane = tid & 63, wave = tid >> 6;
  __shared__ float red[4];
  const float* lg = logits + (size_t)b * Yn;
  const float* tg = target + (size_t)b * Yn;

  float m = -INFINITY;
  for (int y = tid; y < Yn; y += 256) m = fmaxf(m, lg[y]);
#pragma unroll
  for (int off = 1; off <= 32; off <<= 1) m = fmaxf(m, __shfl_xor(m, off));
  if (lane == 0) red[wave] = m;
  __syncthreads();
  m = fmaxf(fmaxf(red[0], red[1]), fmaxf(red[2], red[3]));
  __syncthreads();

  float s = 0.f;
  for (int y = tid; y < Yn; y += 256) s += __expf(lg[y] - m);
#pragma unroll
  for (int off = 1; off <= 32; off <<= 1) s += __shfl_xor(s, off);
  if (lane == 0) red[wave] = s;
  __syncthreads();
  s = red[0] + red[1] + red[2] + red[3];
  __syncthreads();
  float lse = m + logf(s);

  float ls = 0.f;
  for (int y = tid; y < Yn; y += 256){
    float xx = lg[y];
    proba[(size_t)b * Yn + y] = xx - lse;
    ls += fmaxf(xx, 0.f) - xx * tg[y] + log1pf(__expf(-fabsf(xx)));
  }
#pragma unroll
  for (int off = 1; off <= 32; off <<= 1) ls += __shfl_xor(ls, off);
  if (lane == 0) red[wave] = ls;
  __syncthreads();
  if (tid == 0) lossp[b] = red[0] + red[1] + red[2] + red[3];
}

__global__ void k4_loss(const float* __restrict__ lossp, float* __restrict__ out){
  if (threadIdx.x == 0){
    float s = 0.f;
    for (int i = 0; i < Bn; i++) s += lossp[i];
    out[142736] = s / 142736.f;
  }
}

// ---------------- launch ----------------
extern "C" void kernel_launch(void* const* d_in, const int* in_sizes, int n_in,
                              void* d_out, int out_size, void* d_ws, size_t ws_size,
                              hipStream_t stream)
{
  const float* x       = (const float*)d_in[0];
  const float* target  = (const float*)d_in[1];
  const float* conv_w  = (const float*)d_in[2];
  const float* conv_b  = (const float*)d_in[3];
  const float* U_w     = (const float*)d_in[4];
  const float* final_w = (const float*)d_in[5];
  const float* final_b = (const float*)d_in[6];
  float* out = (float*)d_out;

  char* ws = (char*)d_ws;
  short* Hp     = (short*)(ws);                 // 16*40*19456 = 12,451,840 B
  float* WT     = (float*)(ws + 12451840);      //   256,000 B
  float* logits = (float*)(ws + 12707840);      //   570,944 B
  float* lossp  = (float*)(ws + 13278784);      //        64 B
  float* invS   = (float*)(ws + 13278848);      //   570,944 B

  float* proba     = out;              // B*Y
  float* alpha_out = out + 142737;     // after proba + loss

  k0_wt<<<dim3(250), dim3(256), 0, stream>>>(conv_w, WT);
  k1_conv<<<dim3(NT, Bn), dim3(256), 0, stream>>>(x, WT, conv_b, Hp);
  k2a_sum<<<dim3(8 * 2 * NYB), dim3(512), 0, stream>>>(Hp, U_w, invS);
  k2b_alpha<<<dim3(8 * 2 * NYB2), dim3(256), 0, stream>>>(Hp, U_w, final_w, final_b,
                                                          invS, logits, alpha_out);
  k3_lsm<<<dim3(Bn), dim3(256), 0, stream>>>(logits, target, proba, lossp);
  k4_loss<<<dim3(1), dim3(64), 0, stream>>>(lossp, out);
}

// Round 5
// 600.944 us; speedup vs baseline: 1.5140x; 1.2733x over previous
//
#include <hip/hip_runtime.h>
#include <math.h>

#define Bn 16
#define Ln 2500
#define En 100
#define FM 50
#define Yn 8921
#define KS 10
#define LP 2501
#define NT 40              // 40 tiles of 64 l (2560 >= 2501)
#define TILE_BYTES 19456   // hA 10240 + hT 9216
#define TILE_SHORTS 9728
#define HT_OFF 5120        // shorts
#define CH_FULL 19         // 1KB chunks per full tile
#define CH_A 10            // chunks covering hA only
#define NW 8               // waves per K2 block
#define YB 128             // y per K2 block
#define NYB 70             // ceil(8921/128)

typedef __attribute__((ext_vector_type(8))) short short8;
typedef __attribute__((ext_vector_type(4))) float f32x4;

union S8 { short8 v; long l2[2]; short s[8]; };

__device__ __forceinline__ short f2bf(float f){
  unsigned u = __float_as_uint(f);
  unsigned r = (u + 0x7fffu + ((u >> 16) & 1u)) >> 16;
  return (short)r;
}

// async 16B/lane global->LDS
__device__ __forceinline__ void g2l16(const void* g, void* l){
  __builtin_amdgcn_global_load_lds(
      (const __attribute__((address_space(1))) unsigned int*)g,
      (__attribute__((address_space(3))) unsigned int*)l, 16, 0, 0);
}

__device__ __forceinline__ void stage_chunks(const char* __restrict__ gbase,
                                             char* lbase, int wave, int lane,
                                             int nch, int nw){
  for (int chunk = wave; chunk < nch; chunk += nw)
    g2l16(gbase + chunk * 1024 + lane * 16, lbase + chunk * 1024 + lane * 16);
}

// ---------------- K0: transpose conv_w (Fm,E,K) -> WT[e*10+k][f(64 pad0)] --------------
__global__ void k0_wt(const float* __restrict__ cw, float* __restrict__ WT){
  int i = blockIdx.x * 256 + threadIdx.x;
  if (i < 64000){
    int f = i & 63, ek = i >> 6;
    WT[i] = (f < FM) ? cw[f * 1000 + ek] : 0.f;
  }
}

// ---------------- K1: conv+bias+tanh -> per-tile blob [hA pad | hT pad] bf16 -----------
__global__ __launch_bounds__(256) void k1_conv(
    const float* __restrict__ x, const float* __restrict__ WT,
    const float* __restrict__ conv_b, short* __restrict__ Hp)
{
  int t = blockIdx.x, b = blockIdx.y, tid = threadIdx.x;
  __shared__ float x_s[100 * 76];       // [e][row(73) pad 76]
  __shared__ short h_t[64 * 69];        // [l][f pad 69]

  int r0 = 64 * t - 5;
  for (int d = tid; d < 7300; d += 256){
    int row = d / 100, e = d - row * 100;
    int gr = r0 + row;
    float v = (gr >= 0 && gr < Ln) ? x[((size_t)b * Ln + gr) * 100 + e] : 0.f;
    x_s[e * 76 + row] = v;
  }
  __syncthreads();

  int f = tid & 63, lsub = tid >> 6;
  float acc[16];
#pragma unroll
  for (int j = 0; j < 16; j++) acc[j] = 0.f;

  for (int e = 0; e < 100; e++){
    float xv[25];
    const float* xr = x_s + e * 76 + lsub * 16;
#pragma unroll
    for (int i = 0; i < 6; i++){
      f32x4 q = *(const f32x4*)(xr + 4 * i);
      xv[4*i+0] = q[0]; xv[4*i+1] = q[1]; xv[4*i+2] = q[2]; xv[4*i+3] = q[3];
    }
    xv[24] = xr[24];
#pragma unroll
    for (int k = 0; k < KS; k++){
      float wv = WT[(e * 10 + k) * 64 + f];
#pragma unroll
      for (int j = 0; j < 16; j++) acc[j] += wv * xv[j + k];
    }
  }

  float bias = (f < FM) ? conv_b[f] : 0.f;
  size_t tbS = (size_t)(b * NT + t) * TILE_SHORTS;
#pragma unroll
  for (int j = 0; j < 16; j++){
    int l = lsub * 16 + j;
    int lgl = 64 * t + l;
    float hv = (lgl < LP && f < FM) ? tanhf(acc[j] + bias) : 0.f;
    short hb = f2bf(hv);
    // hA image: [fgrp(4)][l(64)][20]  (cols 16..19 are unread holes)
    Hp[tbS + (size_t)(f >> 4) * 1280 + (size_t)l * 20 + (f & 15)] = hb;
    h_t[l * 69 + f] = hb;
  }
  __syncthreads();
  int lane = tid & 63, wave = tid >> 6;
#pragma unroll
  for (int i = 0; i < 16; i++){
    int fo = wave + 4 * i;
    // hT image: [f(64)][72]  (cols 64..71 unread holes)
    Hp[tbS + HT_OFF + (size_t)fo * 72 + lane] = h_t[lane * 69 + fo];
  }
}

// ---------------- shared fragment helpers ----------------
__device__ __forceinline__ void scores_tile(const short* __restrict__ h_s,
                                            const S8 bu[2], int c, int g, f32x4 d[4])
{
#pragma unroll
  for (int ms = 0; ms < 4; ms++){
    f32x4 acc = {0.f, 0.f, 0.f, 0.f};
#pragma unroll
    for (int kf = 0; kf < 2; kf++){
      const short* pa = h_s + (2 * kf) * 1280 + (c + 16 * ms) * 20 + 4 * g;
      S8 a;
      a.l2[0] = *(const long*)pa;
      a.l2[1] = *(const long*)(pa + 1280);
      acc = __builtin_amdgcn_mfma_f32_16x16x32_bf16(a.v, bu[kf].v, acc, 0, 0, 0);
    }
    d[ms] = acc;
  }
}

__device__ __forceinline__ void load_bu(const float* __restrict__ U_w,
                                        int ywave, int c, int g, S8 bu[2]){
  int yv = ywave + c;
#pragma unroll
  for (int kf = 0; kf < 2; kf++)
#pragma unroll
    for (int i = 0; i < 8; i++){
      int fidx = 4 * g + (i & 3) + 16 * (i >> 2) + 32 * kf;
      float v = (yv < Yn && fidx < FM) ? U_w[yv * FM + fidx] : 0.f;
      bu[kf].s[i] = f2bf(v);
    }
}

// ---------------- K2a: S = sum_l exp(score) -> invS ----------------
__global__ __launch_bounds__(512, 4) void k2a_sum(
    const short* __restrict__ Hp, const float* __restrict__ U_w,
    float* __restrict__ invS_out)
{
  int id = blockIdx.x;
  int xcd = id & 7, rr = id >> 3;           // rr in [0,140)
  int b   = xcd + ((rr >= NYB) ? 8 : 0);
  int y0  = ((rr >= NYB) ? rr - NYB : rr) * YB;

  int tid = threadIdx.x;
  int lane = tid & 63, wave = tid >> 6;
  int c = lane & 15, g = lane >> 4;
  int ywave = y0 + wave * 16;

  __shared__ __align__(16) short buf[2][5120];   // hA only

  S8 bu[2];
  load_bu(U_w, ywave, c, g, bu);

  const char* blob = (const char*)Hp + (size_t)b * NT * TILE_BYTES;

  float S = 0.f;
  int cur = 0;
  stage_chunks(blob, (char*)buf[0], wave, lane, CH_A, NW);
  for (int t = 0; t < NT; t++){
    __syncthreads();
    if (t + 1 < NT)
      stage_chunks(blob + (size_t)(t + 1) * TILE_BYTES, (char*)buf[cur ^ 1], wave, lane, CH_A, NW);
    f32x4 d[4];
    scores_tile(buf[cur], bu, c, g, d);
    if (t < NT - 1){
#pragma unroll
      for (int ms = 0; ms < 4; ms++)
#pragma unroll
        for (int q = 0; q < 4; q++) S += __expf(d[ms][q]);
    } else {
#pragma unroll
      for (int ms = 0; ms < 4; ms++)
#pragma unroll
        for (int q = 0; q < 4; q++){
          int l = 64 * t + 16 * ms + 4 * g + q;
          if (l < LP) S += __expf(d[ms][q]);
        }
    }
    cur ^= 1;
  }
  S += __shfl_xor(S, 16);
  S += __shfl_xor(S, 32);
  if (lane < 16){
    int yv = ywave + lane;
    if (yv < Yn) invS_out[b * Yn + yv] = 1.f / S;
  }
}

// ---------------- K2b: alpha (pipelined full-line writes) + m + logits ----------------
// counted-vmcnt barrier: per tile per wave, issue <=3 staging loads FIRST, then exactly
// 16 stores; at next tile top, vmcnt(16) retires the loads, leaves stores in flight.
__global__ __launch_bounds__(512, 4) void k2b_alpha(
    const short* __restrict__ Hp,
    const float* __restrict__ U_w, const float* __restrict__ final_w,
    const float* __restrict__ final_b, const float* __restrict__ invS_arr,
    float* __restrict__ logits, float* __restrict__ alpha_out,
    float* __restrict__ dump)
{
  int id = blockIdx.x;
  int xcd = id & 7, rr = id >> 3;           // rr in [0,140)
  int b   = xcd + ((rr >= NYB) ? 8 : 0);
  int y0  = ((rr >= NYB) ? rr - NYB : rr) * YB;

  int tid = threadIdx.x;
  int lane = tid & 63, wave = tid >> 6;     // wave 0..7
  int c = lane & 15, g = lane >> 4;
  int ywave = y0 + wave * 16;

  __shared__ __align__(16) short buf[2][TILE_SHORTS];
  __shared__ float awf[NW * 1024];          // per-wave [16 rows][64]: carry<=31 + 32 new

  S8 bu[2];
  load_bu(U_w, ywave, c, g, bu);

  float invS = 0.f;
  { int yv = ywave + c; if (yv < Yn) invS = invS_arr[b * Yn + yv]; }

  // alpha row phase: float index of (y,0) is 142737 + (b*8921+y)*2501 ; mod 32:
  int Kf = (17 + 29 * b + 5 * ywave) & 31;
  int fc = (Kf + 5 * c) & 31;

  f32x4 m2[4];
#pragma unroll
  for (int fs = 0; fs < 4; fs++) m2[fs] = (f32x4){0.f, 0.f, 0.f, 0.f};

  const char* blob = (const char*)Hp + (size_t)b * NT * TILE_BYTES;
  float* aw = awf + wave * 1024;
  float* dumpf = dump + (size_t)id * 64;

  int cur = 0;
  stage_chunks(blob, (char*)buf[0], wave, lane, CH_FULL, NW);
  for (int t = 0; t < NT; t++){
    if (t == 0) asm volatile("s_waitcnt vmcnt(0) lgkmcnt(0)" ::: "memory");
    else        asm volatile("s_waitcnt vmcnt(16) lgkmcnt(0)" ::: "memory");
    __builtin_amdgcn_s_barrier();
    if (t + 1 < NT)
      stage_chunks(blob + (size_t)(t + 1) * TILE_BYTES, (char*)buf[cur ^ 1], wave, lane, CH_FULL, NW);
    __builtin_amdgcn_sched_barrier(0);      // pin: loads issued before everything below

    const short* h_s  = buf[cur];
    const short* ht_s = buf[cur] + HT_OFF;
    f32x4 d[4];
    scores_tile(h_s, bu, c, g, d);
    float a[16];
    if (t < NT - 1){
#pragma unroll
      for (int ms = 0; ms < 4; ms++)
#pragma unroll
        for (int q = 0; q < 4; q++) a[ms * 4 + q] = __expf(d[ms][q]) * invS;
    } else {
#pragma unroll
      for (int ms = 0; ms < 4; ms++)
#pragma unroll
        for (int q = 0; q < 4; q++){
          int l = 64 * t + 16 * ms + 4 * g + q;
          a[ms * 4 + q] = (l < LP) ? __expf(d[ms][q]) * invS : 0.f;
        }
    }

    // GEMM2: m += alpha * h   (A2 repacked in-lane from scores^T fragments)
#pragma unroll
    for (int kl = 0; kl < 2; kl++){
      S8 a2;
#pragma unroll
      for (int i = 0; i < 8; i++)
        a2.s[i] = f2bf(a[(2 * kl + (i >> 2)) * 4 + (i & 3)]);
#pragma unroll
      for (int fs = 0; fs < 4; fs++){
        const short* pb = ht_s + (16 * fs + c) * 72 + 4 * g + 32 * kl;
        S8 b2;
        b2.l2[0] = *(const long*)pb;
        b2.l2[1] = *(const long*)(pb + 16);
        m2[fs] = __builtin_amdgcn_mfma_f32_16x16x32_bf16(a2.v, b2.v, m2[fs], 0, 0, 0);
      }
    }

    // alpha out: two half-rounds of 32 cols; every store is a full 128B line,
    // unconditional (OOB lanes redirected to dump) -> exactly 16 stores/wave/tile
#pragma unroll
    for (int hs = 0; hs < 2; hs++){
      // scatter 32 new alphas at row phase fc -> positions [fc, fc+32) (<=63)
#pragma unroll
      for (int mh = 0; mh < 2; mh++)
#pragma unroll
        for (int q = 0; q < 4; q++)
          aw[c * 64 + fc + 16 * mh + 4 * g + q] = a[(2 * hs + mh) * 4 + q];
      // store cols [0,32) of each row: 8 wave-stores (2 rows each)
#pragma unroll
      for (int i = 0; i < 8; i++){
        int jj  = 2 * i + (lane >> 5);
        int k32 = lane & 31;
        int fj  = (Kf + 5 * jj) & 31;
        int gcol = 64 * t + 32 * hs - fj + k32;
        float v = aw[jj * 64 + k32];
        int yj = ywave + jj;
        bool ok = (gcol >= 0) & (gcol < LP) & (yj < Yn);
        float* dst = ok ? (alpha_out + (size_t)(b * Yn + yj) * LP + gcol)
                        : (dumpf + lane);
        __builtin_nontemporal_store(v, dst);
      }
      // shift carry [32, 32+fj) -> [0, fj)
#pragma unroll
      for (int i = 0; i < 8; i++){
        int jj  = 2 * i + (lane >> 5);
        int k32 = lane & 31;
        int fj  = (Kf + 5 * jj) & 31;
        if (k32 < fj) aw[jj * 64 + k32] = aw[jj * 64 + 32 + k32];
      }
    }
    cur ^= 1;
  }

  // ---- epilogue: logits ----
  float part[4];
#pragma unroll
  for (int q = 0; q < 4; q++){
    int yy = ywave + 4 * g + q;
    float p = 0.f;
    if (yy < Yn){
#pragma unroll
      for (int fs = 0; fs < 4; fs++){
        int fcol = fs * 16 + c;
        if (fcol < FM) p += m2[fs][q] * final_w[yy * FM + fcol];
      }
    }
#pragma unroll
    for (int off = 1; off <= 8; off <<= 1) p += __shfl_xor(p, off);
    part[q] = p;
  }
  if (c == 0){
#pragma unroll
    for (int q = 0; q < 4; q++){
      int yy = ywave + 4 * g + q;
      if (yy < Yn) logits[(size_t)b * Yn + yy] = part[q] + final_b[yy];
    }
  }
}

// ---------------- K3: log_softmax over Y + BCE loss partials ----------------
__global__ __launch_bounds__(256) void k3_lsm(
    const float* __restrict__ logits, const float* __restrict__ target,
    float* __restrict__ proba, float* __restrict__ lossp)
{
  int b = blockIdx.x, tid = threadIdx.x;
  int lane = tid & 63, wave = tid >> 6;
  __shared__ float red[4];
  const float* lg = logits + (size_t)b * Yn;
  const float* tg = target + (size_t)b * Yn;

  float m = -INFINITY;
  for (int y = tid; y < Yn; y += 256) m = fmaxf(m, lg[y]);
#pragma unroll
  for (int off = 1; off <= 32; off <<= 1) m = fmaxf(m, __shfl_xor(m, off));
  if (lane == 0) red[wave] = m;
  __syncthreads();
  m = fmaxf(fmaxf(red[0], red[1]), fmaxf(red[2], red[3]));
  __syncthreads();

  float s = 0.f;
  for (int y = tid; y < Yn; y += 256) s += __expf(lg[y] - m);
#pragma unroll
  for (int off = 1; off <= 32; off <<= 1) s += __shfl_xor(s, off);
  if (lane == 0) red[wave] = s;
  __syncthreads();
  s = red[0] + red[1] + red[2] + red[3];
  __syncthreads();
  float lse = m + logf(s);

  float ls = 0.f;
  for (int y = tid; y < Yn; y += 256){
    float xx = lg[y];
    proba[(size_t)b * Yn + y] = xx - lse;
    ls += fmaxf(xx, 0.f) - xx * tg[y] + log1pf(__expf(-fabsf(xx)));
  }
#pragma unroll
  for (int off = 1; off <= 32; off <<= 1) ls += __shfl_xor(ls, off);
  if (lane == 0) red[wave] = ls;
  __syncthreads();
  if (tid == 0) lossp[b] = red[0] + red[1] + red[2] + red[3];
}

__global__ void k4_loss(const float* __restrict__ lossp, float* __restrict__ out){
  if (threadIdx.x == 0){
    float s = 0.f;
    for (int i = 0; i < Bn; i++) s += lossp[i];
    out[142736] = s / 142736.f;
  }
}

// ---------------- launch ----------------
extern "C" void kernel_launch(void* const* d_in, const int* in_sizes, int n_in,
                              void* d_out, int out_size, void* d_ws, size_t ws_size,
                              hipStream_t stream)
{
  const float* x       = (const float*)d_in[0];
  const float* target  = (const float*)d_in[1];
  const float* conv_w  = (const float*)d_in[2];
  const float* conv_b  = (const float*)d_in[3];
  const float* U_w     = (const float*)d_in[4];
  const float* final_w = (const float*)d_in[5];
  const float* final_b = (const float*)d_in[6];
  float* out = (float*)d_out;

  char* ws = (char*)d_ws;
  short* Hp     = (short*)(ws);                 // 16*40*19456 = 12,451,840 B
  float* WT     = (float*)(ws + 12451840);      //   256,000 B
  float* logits = (float*)(ws + 12707840);      //   570,944 B
  float* lossp  = (float*)(ws + 13278784);      //        64 B
  float* invS   = (float*)(ws + 13278848);      //   570,944 B
  float* dump   = (float*)(ws + 13849792);      //   286,720 B  (1120 blocks * 256B)

  float* proba     = out;              // B*Y
  float* alpha_out = out + 142737;     // after proba + loss

  k0_wt<<<dim3(250), dim3(256), 0, stream>>>(conv_w, WT);
  k1_conv<<<dim3(NT, Bn), dim3(256), 0, stream>>>(x, WT, conv_b, Hp);
  k2a_sum<<<dim3(8 * 2 * NYB), dim3(512), 0, stream>>>(Hp, U_w, invS);
  k2b_alpha<<<dim3(8 * 2 * NYB), dim3(512), 0, stream>>>(Hp, U_w, final_w, final_b,
                                                         invS, logits, alpha_out, dump);
  k3_lsm<<<dim3(Bn), dim3(256), 0, stream>>>(logits, target, proba, lossp);
  k4_loss<<<dim3(1), dim3(64), 0, stream>>>(lossp, out);
}